// Round 3
// baseline (103.070 us; speedup 1.0000x reference)
//
#include <hip/hip_runtime.h>

#define DIM 64
#define HW 4096          // 64*64
#define NELEM 8388608.0f // 32*64*4096
#define NBLK 1024        // 128-col tiles

typedef __attribute__((ext_vector_type(8))) short short8;   // 8 x bf16
typedef __attribute__((ext_vector_type(4))) float f32x4;
typedef __attribute__((ext_vector_type(2))) float f32x2;

__device__ __forceinline__ unsigned short f2bf(float f) {
  unsigned int u = __builtin_bit_cast(unsigned int, f);
  u += 0x7fffu + ((u >> 16) & 1u);            // round-to-nearest-even
  return (unsigned short)(u >> 16);
}

__device__ __forceinline__ float wave_sum(float v) {
  #pragma unroll
  for (int off = 32; off >= 1; off >>= 1) v += __shfl_xor(v, off);
  return v;
}

// ws layout (bytes):
//  [0,     4096)  per-block partial sum(x^2)      (1024 floats)
//  [4096,  8192)  per-block partial sum(min d2')  (1024 floats)

// ---- main: 1024 blocks x 4 waves; 128-col tile; codes split across waves --
// R2: vq_prep ELIMINATED.  Each wave converts its own 128 codes fp32->bf16
// A-fragments in REGISTERS (areg[8][2], 64 VGPR) while the X nontemporal
// loads are in flight; ||c||^2 computed in-wave (butterfly shfl).  Main loop
// is fully memoryless (reg MFMA + VALU).  h-outer keeps bfrag half-resident
// (32 VGPR); launch_bounds(256,3) = 170-VGPR budget, 3 blocks/CU — loop has
// no memory ops left to hide, and 1024 blocks over 768 residency slots
// stagger the HBM load/store phases.
// NO atomics/fences (same-addr device atomics ~100us convoy, prev session).
__global__ __launch_bounds__(256, 3)
void vq_main(const float* __restrict__ X, const float* __restrict__ CB,
             float* __restrict__ out,
             float* __restrict__ pA, float* __restrict__ pB) {
  __shared__ __align__(16) unsigned short XF[16 * 64 * 8]; // 16 KB frag-order
  __shared__ float mW[4][128];                // per-wave packed mins per col
  __shared__ float red[8];

  const int t   = threadIdx.x;
  const int bid = blockIdx.x;
  // XCD-chunked swizzle: XCD x owns logical blocks [x*128,(x+1)*128)
  const int L   = ((bid & 7) << 7) | (bid >> 3);
  const int n   = L >> 5;                     // image (32 tiles of 128 cols)
  const int hw0 = (L & 31) << 7;              // 128-col tile
  const int wv  = t >> 6, lane = t & 63;
  const int g   = lane >> 4, lcol = lane & 15;

  const float* Xg = X + n * (DIM * HW) + hw0;

  // ---- issue X loads first (HBM, nontemporal) ----------------------------
  const int db8 = t >> 5;                     // 0..7 row-group
  const int cp  = t & 31;                     // 0..31 col-pair
  const int kss = db8 >> 2, gs = db8 & 3;
  f32x2 v[2][8];
  #pragma unroll
  for (int h = 0; h < 2; ++h)
    #pragma unroll
    for (int j = 0; j < 8; ++j)
      v[h][j] = __builtin_nontemporal_load(
          (const f32x2*)(Xg + (db8 * 8 + j) * HW + h * 64 + cp * 2));

  // ---- A-frags: this wave's 128 codes, fp32 CB -> bf16(-2c) in regs ------
  // slot (chunk,ks,lane): code = chunk*16+lcol, dims ks*32+g*8 .. +7
  // (overlaps the X HBM latency; CB is 128KB, L2/L3-hot)
  short8 areg[8][2];
  float cnv[8];
  #pragma unroll
  for (int i = 0; i < 8; ++i) {
    const int code = (wv * 8 + i) * 16 + lcol;
    float pc = 0.f;
    #pragma unroll
    for (int ks = 0; ks < 2; ++ks) {
      const float* cpp = CB + code * DIM + ks * 32 + g * 8;
      float4 u0 = *(const float4*)cpp;
      float4 u1 = *(const float4*)(cpp + 4);
      pc += u0.x*u0.x + u0.y*u0.y + u0.z*u0.z + u0.w*u0.w
          + u1.x*u1.x + u1.y*u1.y + u1.z*u1.z + u1.w*u1.w;
      short8 p;
      p[0]=(short)f2bf(-2.f*u0.x); p[1]=(short)f2bf(-2.f*u0.y);
      p[2]=(short)f2bf(-2.f*u0.z); p[3]=(short)f2bf(-2.f*u0.w);
      p[4]=(short)f2bf(-2.f*u1.x); p[5]=(short)f2bf(-2.f*u1.y);
      p[6]=(short)f2bf(-2.f*u1.z); p[7]=(short)f2bf(-2.f*u1.w);
      areg[i][ks] = p;
    }
    pc += __shfl_xor(pc, 16);                 // sum the 4 g-groups
    pc += __shfl_xor(pc, 32);                 // -> exact ||c||^2, uniform/g
    cnv[i] = pc;
  }

  // ---- consume X: sum(x^2) + bf16 pack into fragment-order LDS -----------
  float sx2 = 0.f;
  #pragma unroll
  for (int h = 0; h < 2; ++h)
    #pragma unroll
    for (int j = 0; j < 8; ++j)
      sx2 += v[h][j].x * v[h][j].x + v[h][j].y * v[h][j].y;
  #pragma unroll
  for (int h = 0; h < 2; ++h) {
    #pragma unroll
    for (int ci = 0; ci < 2; ++ci) {
      const int cl   = cp * 2 + ci;           // 0..63 within half
      const int cb   = h * 4 + (cl >> 4);     // 0..7 col-block
      const int slot = (cb * 2 + kss) * 64 + gs * 16 + (cl & 15);
      const int swz  = slot ^ ((slot >> 3) & 7);
      short8 w;
      #pragma unroll
      for (int j = 0; j < 8; ++j)
        w[j] = (short)f2bf(ci ? v[h][j].y : v[h][j].x);
      *(short8*)&XF[swz * 8] = w;
    }
  }
  __syncthreads();

  // ---- main loop: fully in-register MFMA + tag/min -----------------------
  float m1[8];
  #pragma unroll
  for (int cb = 0; cb < 8; ++cb) m1[cb] = 3.0e38f;

  const int swzl = lane ^ ((lane >> 3) & 7);
  #pragma unroll
  for (int h = 0; h < 2; ++h) {
    short8 bfrag[4][2];                       // half-resident (32 VGPR)
    #pragma unroll
    for (int cb2 = 0; cb2 < 4; ++cb2)
      #pragma unroll
      for (int ks = 0; ks < 2; ++ks)
        bfrag[cb2][ks] =
            *(const short8*)&XF[(((h * 4 + cb2) * 2 + ks) * 64 + swzl) * 8];

    #pragma unroll
    for (int i = 0; i < 8; ++i) {
      const int codebase = (wv * 8 + i) * 16 + g * 4;
      f32x4 cn;
      cn[0] = __shfl(cnv[i], g * 4 + 0, 16);  // broadcast within 16-seg
      cn[1] = __shfl(cnv[i], g * 4 + 1, 16);
      cn[2] = __shfl(cnv[i], g * 4 + 2, 16);
      cn[3] = __shfl(cnv[i], g * 4 + 3, 16);
      #pragma unroll
      for (int cb2 = 0; cb2 < 4; ++cb2) {
        f32x4 acc = cn;
        acc = __builtin_amdgcn_mfma_f32_16x16x32_bf16(areg[i][0], bfrag[cb2][0], acc, 0, 0, 0);
        acc = __builtin_amdgcn_mfma_f32_16x16x32_bf16(areg[i][1], bfrag[cb2][1], acc, 0, 0, 0);
        #pragma unroll
        for (int r = 0; r < 4; ++r) {
          unsigned int vb = __builtin_bit_cast(unsigned int, acc[r]);
          vb = (vb & 0xFFFFFE00u) | ((unsigned)(codebase + r) & 0x1FFu);
          m1[h * 4 + cb2] = fminf(m1[h * 4 + cb2], __builtin_bit_cast(float, vb));
        }
      }
    }
  }

  // combine lane-groups (disjoint code subsets, same col)
  #pragma unroll
  for (int cb = 0; cb < 8; ++cb) {
    m1[cb] = fminf(m1[cb], __shfl_xor(m1[cb], 16));
    m1[cb] = fminf(m1[cb], __shfl_xor(m1[cb], 32));
    if (g == 0) mW[wv][cb * 16 + lcol] = m1[cb];
  }
  __syncthreads();

  // ---- final per-col argmin + epilogue, two 64-col passes ----------------
  float msum = 0.f;
  #pragma unroll
  for (int h = 0; h < 2; ++h) {
    const int c = h * 64 + lane;
    const float p = fminf(fminf(mW[0][c], mW[1][c]),
                          fminf(mW[2][c], mW[3][c]));
    const unsigned int b = __builtin_bit_cast(unsigned int, p);
    const int k = (int)(b & 511u);
    msum += __builtin_bit_cast(float, b & 0xFFFFFE00u);

    const float* cq = CB + k * DIM + wv * 16; // L2-hot gather
    float* op = out + 1 + n * (DIM * HW) + hw0 + c;
    #pragma unroll
    for (int i = 0; i < 4; ++i) {
      float4 u = *(const float4*)(cq + i * 4);
      __builtin_nontemporal_store(u.x, &op[(wv*16 + i*4 + 0) * HW]);
      __builtin_nontemporal_store(u.y, &op[(wv*16 + i*4 + 1) * HW]);
      __builtin_nontemporal_store(u.z, &op[(wv*16 + i*4 + 2) * HW]);
      __builtin_nontemporal_store(u.w, &op[(wv*16 + i*4 + 3) * HW]);
    }
  }

  // ---- loss partials (no atomics; vq_fin reduces) ----
  float w1 = wave_sum(sx2);
  if (lane == 0) red[wv] = w1;
  if (wv == 0) {
    float w2 = wave_sum(msum);                // each col counted once
    if (lane == 0) red[4] = w2;
  }
  __syncthreads();
  if (t == 0) {
    pA[bid] = red[0] + red[1] + red[2] + red[3];
    pB[bid] = red[4];
  }
}

__global__ void vq_fin(const float* __restrict__ pA,
                       const float* __restrict__ pB,
                       float* __restrict__ out) {
  const int t = threadIdx.x;                  // 512 threads, 1024 partials
  f32x2 a = *(const f32x2*)&pA[t * 2];
  f32x2 c = *(const f32x2*)&pB[t * 2];
  float v = a.x + a.y + c.x + c.y;
  v = wave_sum(v);
  __shared__ float r[8];
  if ((t & 63) == 0) r[t >> 6] = v;
  __syncthreads();
  if (t == 0) {
    float s = 0.f;
    #pragma unroll
    for (int i = 0; i < 8; ++i) s += r[i];
    out[0] = 1.25f * s * (1.0f / NELEM);
  }
}

extern "C" void kernel_launch(void* const* d_in, const int* in_sizes, int n_in,
                              void* d_out, int out_size, void* d_ws, size_t ws_size,
                              hipStream_t stream) {
  const float* X  = (const float*)d_in[0];   // [32,64,64,64] fp32
  const float* CB = (const float*)d_in[1];   // [512,64] fp32
  float* out = (float*)d_out;                // [0]=loss, [1..]=quantized_st
  char* ws = (char*)d_ws;
  float* pA = (float*)ws;
  float* pB = (float*)(ws + 4096);
  (void)in_sizes; (void)n_in; (void)out_size; (void)ws_size;

  vq_main<<<NBLK, 256, 0, stream>>>(X, CB, out, pA, pB);
  vq_fin<<<1, 512, 0, stream>>>(pA, pB, out);
}

// Round 4
// 37.023 us; speedup vs baseline: 2.7840x; 2.7840x over previous
//
#include <hip/hip_runtime.h>

#define DIM 64
#define HW 4096          // 64*64
#define NELEM 8388608.0f // 32*64*4096
#define NBLK 1024        // 128-col tiles

typedef __attribute__((ext_vector_type(8))) short short8;   // 8 x bf16
typedef __attribute__((ext_vector_type(4))) float f32x4;
typedef __attribute__((ext_vector_type(2))) float f32x2;

__device__ __forceinline__ unsigned short f2bf(float f) {
  unsigned int u = __builtin_bit_cast(unsigned int, f);
  u += 0x7fffu + ((u >> 16) & 1u);            // round-to-nearest-even
  return (unsigned short)(u >> 16);
}

__device__ __forceinline__ float wave_sum(float v) {
  #pragma unroll
  for (int off = 32; off >= 1; off >>= 1) v += __shfl_xor(v, off);
  return v;
}

// ws layout (bytes):
//  [0,      65536)  A-frags: bf16(-2*codebook), MFMA-fragment order (L2-hot)
//  [65536,  67584)  cnorm fp32 [512]
//  [67584,  71680)  per-block partial sum(x^2)      (1024 floats)
//  [75776,  79872)  per-block partial sum(min d2')  (1024 floats)

// ---------------- prep: codebook -> fragment order (once per call) ---------
__global__ void vq_prep(const float* __restrict__ CB,
                        unsigned short* __restrict__ aFg,
                        float* __restrict__ cn) {
  const int t = threadIdx.x;
  const int s = blockIdx.x * 512 + t;     // 0..4095 fragment slots
  const int chunk = s >> 7, ks = (s >> 6) & 1, ls = s & 63;
  const int code = chunk * 16 + (ls & 15);
  const int d0 = ks * 32 + (ls >> 4) * 8;
  const float* cp = CB + code * DIM + d0;
  float4 u0 = *(const float4*)cp;
  float4 u1 = *(const float4*)(cp + 4);
  short8 p;
  p[0]=(short)f2bf(-2.f*u0.x); p[1]=(short)f2bf(-2.f*u0.y);
  p[2]=(short)f2bf(-2.f*u0.z); p[3]=(short)f2bf(-2.f*u0.w);
  p[4]=(short)f2bf(-2.f*u1.x); p[5]=(short)f2bf(-2.f*u1.y);
  p[6]=(short)f2bf(-2.f*u1.z); p[7]=(short)f2bf(-2.f*u1.w);
  *(short8*)&aFg[s * 8] = p;
  if (blockIdx.x == 0) {                  // exact fp32 ||c_k||^2
    const float* c2 = CB + t * DIM;
    float sn = 0.f;
    #pragma unroll
    for (int i = 0; i < 16; ++i) {
      float4 u = *(const float4*)(c2 + i * 4);
      sn += u.x*u.x + u.y*u.y + u.z*u.z + u.w*u.w;
    }
    cn[t] = sn;
  }
}

// ---- main: 1024 blocks x 4 waves; 128-col tile; codes split across waves --
// R4: revert R2's in-register CB conversion (VGPR 84 + 209MB WRITE_SIZE =
// scratch-spill traffic; prep restored).  vs R1 (34.25us proven): (a) i-loop
// unroll 2->4 so aFg L2 loads pipeline ~2 iterations deep; (b) tag/min as a
// min3-fusable tree (3 instrs + 1-deep m1 chain, was 4 sequential).
// NO atomics/fences (same-addr device atomics ~100us convoy, prev session).
__global__ __launch_bounds__(256, 4)
void vq_main(const float* __restrict__ X, const float* __restrict__ CB,
             const unsigned short* __restrict__ aFg,
             const float* __restrict__ cng,
             float* __restrict__ out,
             float* __restrict__ pA, float* __restrict__ pB) {
  __shared__ __align__(16) unsigned short XF[16 * 64 * 8]; // 16 KB frag-order
  __shared__ float mW[4][128];                // per-wave packed mins per col
  __shared__ float red[8];

  const int t   = threadIdx.x;
  const int bid = blockIdx.x;
  // XCD-chunked swizzle: XCD x owns logical blocks [x*128,(x+1)*128)
  const int L   = ((bid & 7) << 7) | (bid >> 3);
  const int n   = L >> 5;                     // image (32 tiles of 128 cols)
  const int hw0 = (L & 31) << 7;              // 128-col tile
  const int wv  = t >> 6, lane = t & 63;
  const int g   = lane >> 4, lcol = lane & 15;

  const float* Xg = X + n * (DIM * HW) + hw0;

  // ---- stage X tile fp32->bf16 straight into fragment order --------------
  // thread t: d-rows db8*8..db8*8+7, cols {h*64 + cp*2, +1} for h=0,1
  const int db8 = t >> 5;                     // 0..7
  const int cp  = t & 31;                     // 0..31
  const int kss = db8 >> 2, gs = db8 & 3;
  f32x2 v[2][8];
  #pragma unroll
  for (int h = 0; h < 2; ++h)
    #pragma unroll
    for (int j = 0; j < 8; ++j)
      v[h][j] = __builtin_nontemporal_load(
          (const f32x2*)(Xg + (db8 * 8 + j) * HW + h * 64 + cp * 2));
  float sx2 = 0.f;
  #pragma unroll
  for (int h = 0; h < 2; ++h)
    #pragma unroll
    for (int j = 0; j < 8; ++j)
      sx2 += v[h][j].x * v[h][j].x + v[h][j].y * v[h][j].y;
  #pragma unroll
  for (int h = 0; h < 2; ++h) {
    #pragma unroll
    for (int ci = 0; ci < 2; ++ci) {
      const int cl   = cp * 2 + ci;           // 0..63 within half
      const int cb   = h * 4 + (cl >> 4);     // 0..7 col-block
      const int slot = (cb * 2 + kss) * 64 + gs * 16 + (cl & 15);
      const int swz  = slot ^ ((slot >> 3) & 7);
      short8 w;
      #pragma unroll
      for (int j = 0; j < 8; ++j)
        w[j] = (short)f2bf(ci ? v[h][j].y : v[h][j].x);
      *(short8*)&XF[swz * 8] = w;
    }
  }
  __syncthreads();

  // ---- B-frags from LDS: 16x ds_read_b128, conflict-free, resident -------
  const int swzl = lane ^ ((lane >> 3) & 7);
  short8 bfrag[2][4][2];
  #pragma unroll
  for (int h = 0; h < 2; ++h)
    #pragma unroll
    for (int cb2 = 0; cb2 < 4; ++cb2)
      #pragma unroll
      for (int ks = 0; ks < 2; ++ks)
        bfrag[h][cb2][ks] =
            *(const short8*)&XF[(((h * 4 + cb2) * 2 + ks) * 64 + swzl) * 8];

  // ---- this wave scans 128 codes = 8 chunks of 16, over all 128 cols -----
  float m1[8];
  #pragma unroll
  for (int cb = 0; cb < 8; ++cb) m1[cb] = 3.0e38f;

  const int chunk0 = wv * 8;
  #pragma unroll 4
  for (int i = 0; i < 8; ++i) {
    const int chunk = chunk0 + i;
    const short8 a0 = *(const short8*)&aFg[((chunk*2 + 0) * 64 + lane) * 8];
    const short8 a1 = *(const short8*)&aFg[((chunk*2 + 1) * 64 + lane) * 8];
    const int codebase = chunk * 16 + g * 4;
    const f32x4 cn = *(const f32x4*)&cng[codebase];
    #pragma unroll
    for (int h = 0; h < 2; ++h) {
      #pragma unroll
      for (int cb2 = 0; cb2 < 4; ++cb2) {
        f32x4 acc = cn;
        acc = __builtin_amdgcn_mfma_f32_16x16x32_bf16(a0, bfrag[h][cb2][0], acc, 0, 0, 0);
        acc = __builtin_amdgcn_mfma_f32_16x16x32_bf16(a1, bfrag[h][cb2][1], acc, 0, 0, 0);
        // tag (v_bfi) then min3-fusable tree: 1-deep dep chain on m1
        float tg[4];
        #pragma unroll
        for (int r = 0; r < 4; ++r) {
          unsigned int vb = __builtin_bit_cast(unsigned int, acc[r]);
          vb = (vb & 0xFFFFFE00u) | ((unsigned)(codebase + r) & 0x1FFu);
          tg[r] = __builtin_bit_cast(float, vb);
        }
        const float u0 = fminf(tg[0], tg[1]);
        const float u1 = fminf(tg[2], tg[3]);
        m1[h * 4 + cb2] = fminf(fminf(m1[h * 4 + cb2], u0), u1); // v_min3
      }
    }
  }

  // combine lane-groups (disjoint code subsets, same col)
  #pragma unroll
  for (int cb = 0; cb < 8; ++cb) {
    m1[cb] = fminf(m1[cb], __shfl_xor(m1[cb], 16));
    m1[cb] = fminf(m1[cb], __shfl_xor(m1[cb], 32));
    if (g == 0) mW[wv][cb * 16 + lcol] = m1[cb];
  }
  __syncthreads();

  // ---- final per-col argmin + epilogue, two 64-col passes ----------------
  float msum = 0.f;
  #pragma unroll
  for (int h = 0; h < 2; ++h) {
    const int c = h * 64 + lane;
    const float p = fminf(fminf(mW[0][c], mW[1][c]),
                          fminf(mW[2][c], mW[3][c]));
    const unsigned int b = __builtin_bit_cast(unsigned int, p);
    const int k = (int)(b & 511u);
    msum += __builtin_bit_cast(float, b & 0xFFFFFE00u);

    const float* cq = CB + k * DIM + wv * 16; // L2-hot gather
    float* op = out + 1 + n * (DIM * HW) + hw0 + c;
    #pragma unroll
    for (int i = 0; i < 4; ++i) {
      float4 u = *(const float4*)(cq + i * 4);
      __builtin_nontemporal_store(u.x, &op[(wv*16 + i*4 + 0) * HW]);
      __builtin_nontemporal_store(u.y, &op[(wv*16 + i*4 + 1) * HW]);
      __builtin_nontemporal_store(u.z, &op[(wv*16 + i*4 + 2) * HW]);
      __builtin_nontemporal_store(u.w, &op[(wv*16 + i*4 + 3) * HW]);
    }
  }

  // ---- loss partials (no atomics; vq_fin reduces) ----
  float w1 = wave_sum(sx2);
  if (lane == 0) red[wv] = w1;
  if (wv == 0) {
    float w2 = wave_sum(msum);                // each col counted once
    if (lane == 0) red[4] = w2;
  }
  __syncthreads();
  if (t == 0) {
    pA[bid] = red[0] + red[1] + red[2] + red[3];
    pB[bid] = red[4];
  }
}

__global__ void vq_fin(const float* __restrict__ pA,
                       const float* __restrict__ pB,
                       float* __restrict__ out) {
  const int t = threadIdx.x;                  // 512 threads, 1024 partials
  f32x2 a = *(const f32x2*)&pA[t * 2];
  f32x2 c = *(const f32x2*)&pB[t * 2];
  float v = a.x + a.y + c.x + c.y;
  v = wave_sum(v);
  __shared__ float r[8];
  if ((t & 63) == 0) r[t >> 6] = v;
  __syncthreads();
  if (t == 0) {
    float s = 0.f;
    #pragma unroll
    for (int i = 0; i < 8; ++i) s += r[i];
    out[0] = 1.25f * s * (1.0f / NELEM);
  }
}

extern "C" void kernel_launch(void* const* d_in, const int* in_sizes, int n_in,
                              void* d_out, int out_size, void* d_ws, size_t ws_size,
                              hipStream_t stream) {
  const float* X  = (const float*)d_in[0];   // [32,64,64,64] fp32
  const float* CB = (const float*)d_in[1];   // [512,64] fp32
  float* out = (float*)d_out;                // [0]=loss, [1..]=quantized_st
  char* ws = (char*)d_ws;
  unsigned short* aFg = (unsigned short*)ws;
  float* cn = (float*)(ws + 65536);
  float* pA = (float*)(ws + 67584);
  float* pB = (float*)(ws + 75776);
  (void)in_sizes; (void)n_in; (void)out_size; (void)ws_size;

  vq_prep<<<8, 512, 0, stream>>>(CB, aFg, cn);
  vq_main<<<NBLK, 256, 0, stream>>>(X, CB, aFg, cn, out, pA, pB);
  vq_fin<<<1, 512, 0, stream>>>(pA, pB, out);
}

// Round 6
// 34.913 us; speedup vs baseline: 2.9522x; 1.0604x over previous
//
#include <hip/hip_runtime.h>

#define DIM 64
#define HW 4096          // 64*64
#define NELEM 8388608.0f // 32*64*4096
#define NBLK 512         // 512 blocks x 2 adjacent 128-col tiles

typedef __attribute__((ext_vector_type(8))) short short8;   // 8 x bf16
typedef __attribute__((ext_vector_type(4))) float f32x4;
typedef __attribute__((ext_vector_type(2))) float f32x2;

__device__ __forceinline__ unsigned short f2bf(float f) {
  unsigned int u = __builtin_bit_cast(unsigned int, f);
  u += 0x7fffu + ((u >> 16) & 1u);            // round-to-nearest-even
  return (unsigned short)(u >> 16);
}

__device__ __forceinline__ float wave_sum(float v) {
  #pragma unroll
  for (int off = 32; off >= 1; off >>= 1) v += __shfl_xor(v, off);
  return v;
}

// ws layout (bytes):
//  [0,      65536)  A-frags: bf16(-2*codebook), MFMA-fragment order (L2-hot)
//  [65536,  67584)  cnorm fp32 [512]
//  [67584,  69632)  per-block partial sum(x^2)      (512 floats)
//  [75776,  77824)  per-block partial sum(min d2')  (512 floats)

// ---------------- prep: codebook -> fragment order (once per call) ---------
__global__ void vq_prep(const float* __restrict__ CB,
                        unsigned short* __restrict__ aFg,
                        float* __restrict__ cn) {
  const int t = threadIdx.x;
  const int s = blockIdx.x * 512 + t;     // 0..4095 fragment slots
  const int chunk = s >> 7, ks = (s >> 6) & 1, ls = s & 63;
  const int code = chunk * 16 + (ls & 15);
  const int d0 = ks * 32 + (ls >> 4) * 8;
  const float* cp = CB + code * DIM + d0;
  float4 u0 = *(const float4*)cp;
  float4 u1 = *(const float4*)(cp + 4);
  short8 p;
  p[0]=(short)f2bf(-2.f*u0.x); p[1]=(short)f2bf(-2.f*u0.y);
  p[2]=(short)f2bf(-2.f*u0.z); p[3]=(short)f2bf(-2.f*u0.w);
  p[4]=(short)f2bf(-2.f*u1.x); p[5]=(short)f2bf(-2.f*u1.y);
  p[6]=(short)f2bf(-2.f*u1.z); p[7]=(short)f2bf(-2.f*u1.w);
  *(short8*)&aFg[s * 8] = p;
  if (blockIdx.x == 0) {                  // exact fp32 ||c_k||^2
    const float* c2 = CB + t * DIM;
    float sn = 0.f;
    #pragma unroll
    for (int i = 0; i < 16; ++i) {
      float4 u = *(const float4*)(c2 + i * 4);
      sn += u.x*u.x + u.y*u.y + u.z*u.z + u.w*u.w;
    }
    cn[t] = sn;
  }
}

// ---- main: 512 blocks x 4 waves; TWO adjacent 128-col tiles, pipelined ----
// R5/R6: phase-convoy fix.  R3 calibration: gaps+prep+fin ~3-5us, so vq_main
// itself ~29us vs ~13us phase-sum -> phases were serialized chip-wide (all
// blocks lockstep: load / compute / store with HBM idle during compute).
// Pipeline: issue loads(t1) before compute(t0); pack(t1)+epilogue(t0)
// between barriers; raw s_barrier+lgkmcnt(0) (NOT vmcnt) before compute(t1)
// so t0 stores drain under it.  launch_bounds(256,2): 256-VGPR budget (no
// spill, cf. R3), 512 blocks = exactly 2/CU resident.
// Inner loop = R1's proven body (unroll 2, plain min chain; R4 variants hurt).
// R6 fix: nontemporal builtins need ext_vector types, not HIP float4.
// NO atomics/fences (same-addr device atomics ~100us convoy, prev session).
__global__ __launch_bounds__(256, 2)
void vq_main(const float* __restrict__ X, const float* __restrict__ CB,
             const unsigned short* __restrict__ aFg,
             const float* __restrict__ cng,
             float* __restrict__ out,
             float* __restrict__ pA, float* __restrict__ pB) {
  __shared__ __align__(16) unsigned short XF[16 * 64 * 8]; // 16 KB frag-order
  __shared__ float mW[4][128];                // per-wave packed mins per col
  __shared__ float red[8];

  const int t   = threadIdx.x;
  const int bid = blockIdx.x;
  // XCD-chunked swizzle on tile PAIRS: XCD x owns logical pairs [x*64,..)
  const int Lp  = ((bid & 7) << 6) | (bid >> 3);  // 0..511
  const int tile0 = Lp * 2;                   // even -> same image for pair
  const int n   = tile0 >> 5;
  const int hwA = (tile0 & 31) << 7;
  const int hwB = hwA + 128;                  // adjacent -> store lines merge
  const int wv  = t >> 6, lane = t & 63;
  const int g   = lane >> 4, lcol = lane & 15;
  const int db8 = t >> 5;                     // row-group 0..7
  const int cq  = t & 31;                     // col-quad 0..31
  const int kss = db8 >> 2, gs = db8 & 3;
  const float* Xbase = X + n * (DIM * HW);

  float sx2 = 0.f, msum = 0.f;
  f32x4 v[8];

  // ================= stage helpers (inlined twice) ========================
  // thread (db8,cq): rows db8*8..+7, cols cq*4..+3 (16B/lane loads)
#define LOADX(hw0)                                                          \
  _Pragma("unroll")                                                         \
  for (int j = 0; j < 8; ++j)                                               \
    v[j] = __builtin_nontemporal_load(                                      \
        (const f32x4*)(Xbase + (hw0) + (db8 * 8 + j) * HW + cq * 4));

#define PACKX()                                                             \
  _Pragma("unroll")                                                         \
  for (int j = 0; j < 8; ++j)                                               \
    sx2 += v[j].x*v[j].x + v[j].y*v[j].y + v[j].z*v[j].z + v[j].w*v[j].w;   \
  _Pragma("unroll")                                                         \
  for (int ci = 0; ci < 4; ++ci) {                                          \
    const int c    = cq * 4 + ci;             /* 0..127 */                  \
    const int slot = ((c >> 4) * 2 + kss) * 64 + gs * 16 + (c & 15);        \
    const int swz  = slot ^ ((slot >> 3) & 7);                              \
    short8 w;                                                               \
    _Pragma("unroll")                                                       \
    for (int j = 0; j < 8; ++j)                                             \
      w[j] = (short)f2bf(v[j][ci]);                                         \
    *(short8*)&XF[swz * 8] = w;                                             \
  }

  // R1's proven compute body: bfrag resident, unroll 2, plain min chain
#define COMPUTE_MINRED()                                                    \
  {                                                                         \
    const int swzl = lane ^ ((lane >> 3) & 7);                              \
    short8 bfrag[2][4][2];                                                  \
    _Pragma("unroll")                                                       \
    for (int h = 0; h < 2; ++h)                                             \
      _Pragma("unroll")                                                     \
      for (int cb2 = 0; cb2 < 4; ++cb2)                                     \
        _Pragma("unroll")                                                   \
        for (int ks = 0; ks < 2; ++ks)                                      \
          bfrag[h][cb2][ks] =                                               \
              *(const short8*)&XF[(((h*4+cb2)*2 + ks)*64 + swzl) * 8];      \
    float m1[8];                                                            \
    _Pragma("unroll")                                                       \
    for (int cb = 0; cb < 8; ++cb) m1[cb] = 3.0e38f;                        \
    const int chunk0 = wv * 8;                                              \
    _Pragma("unroll 2")                                                     \
    for (int i = 0; i < 8; ++i) {                                           \
      const int chunk = chunk0 + i;                                         \
      const short8 a0 = *(const short8*)&aFg[((chunk*2+0)*64 + lane) * 8];  \
      const short8 a1 = *(const short8*)&aFg[((chunk*2+1)*64 + lane) * 8];  \
      const int codebase = chunk * 16 + g * 4;                              \
      const f32x4 cn = *(const f32x4*)&cng[codebase];                       \
      _Pragma("unroll")                                                     \
      for (int h = 0; h < 2; ++h) {                                         \
        _Pragma("unroll")                                                   \
        for (int cb2 = 0; cb2 < 4; ++cb2) {                                 \
          f32x4 acc = cn;                                                   \
          acc = __builtin_amdgcn_mfma_f32_16x16x32_bf16(a0, bfrag[h][cb2][0], acc, 0, 0, 0); \
          acc = __builtin_amdgcn_mfma_f32_16x16x32_bf16(a1, bfrag[h][cb2][1], acc, 0, 0, 0); \
          _Pragma("unroll")                                                 \
          for (int r = 0; r < 4; ++r) {                                     \
            unsigned int vb = __builtin_bit_cast(unsigned int, acc[r]);     \
            vb = (vb & 0xFFFFFE00u) | ((unsigned)(codebase + r) & 0x1FFu);  \
            m1[h*4+cb2] = fminf(m1[h*4+cb2], __builtin_bit_cast(float, vb));\
          }                                                                 \
        }                                                                   \
      }                                                                     \
    }                                                                       \
    _Pragma("unroll")                                                       \
    for (int cb = 0; cb < 8; ++cb) {                                        \
      m1[cb] = fminf(m1[cb], __shfl_xor(m1[cb], 16));                       \
      m1[cb] = fminf(m1[cb], __shfl_xor(m1[cb], 32));                       \
      if (g == 0) mW[wv][cb * 16 + lcol] = m1[cb];                          \
    }                                                                       \
  }

#define EPILOGUE(hw0)                                                       \
  _Pragma("unroll")                                                         \
  for (int h = 0; h < 2; ++h) {                                             \
    const int c = h * 64 + lane;                                            \
    const float p = fminf(fminf(mW[0][c], mW[1][c]),                        \
                          fminf(mW[2][c], mW[3][c]));                       \
    const unsigned int b = __builtin_bit_cast(unsigned int, p);             \
    const int k = (int)(b & 511u);                                          \
    msum += __builtin_bit_cast(float, b & 0xFFFFFE00u);                     \
    const float* cqp = CB + k * DIM + wv * 16;  /* L2-hot gather */         \
    float* op = out + 1 + n * (DIM * HW) + (hw0) + c;                       \
    _Pragma("unroll")                                                       \
    for (int i = 0; i < 4; ++i) {                                           \
      float4 u = *(const float4*)(cqp + i * 4);                             \
      __builtin_nontemporal_store(u.x, &op[(wv*16 + i*4 + 0) * HW]);        \
      __builtin_nontemporal_store(u.y, &op[(wv*16 + i*4 + 1) * HW]);        \
      __builtin_nontemporal_store(u.z, &op[(wv*16 + i*4 + 2) * HW]);        \
      __builtin_nontemporal_store(u.w, &op[(wv*16 + i*4 + 3) * HW]);        \
    }                                                                       \
  }

  // ============================ pipeline ==================================
  LOADX(hwA);                                 // t0 X loads (HBM)
  PACKX();                                    // t0 -> XF (waits own loads)
  __syncthreads();                            // vmcnt ~0 here: free

  LOADX(hwB);                                 // issue t1 loads EARLY
  __builtin_amdgcn_sched_barrier(0);          // pin issue before compute

  COMPUTE_MINRED();                           // t0 (aFg L2 + MFMA; HBM busy
                                              //  with t1 loads meanwhile)
  __syncthreads();                            // t1 loads long arrived: cheap

  PACKX();                                    // t1 -> XF (XF reads done)
  EPILOGUE(hwA);                              // t0 gather + nt stores
  // LDS-only barrier: do NOT drain the t0 stores (they fly under compute t1)
  asm volatile("s_waitcnt lgkmcnt(0)" ::: "memory");
  __builtin_amdgcn_sched_barrier(0);
  __builtin_amdgcn_s_barrier();
  __builtin_amdgcn_sched_barrier(0);

  COMPUTE_MINRED();                           // t1 (overwrites mW after bar)
  __syncthreads();                            // t0 stores mostly drained

  EPILOGUE(hwB);                              // t1 gather + nt stores

  // ---- loss partials (no atomics; vq_fin reduces) ----
  float w1 = wave_sum(sx2);
  if (lane == 0) red[wv] = w1;
  if (wv == 0) {
    float w2 = wave_sum(msum);                // each col counted once
    if (lane == 0) red[4] = w2;
  }
  asm volatile("s_waitcnt lgkmcnt(0)" ::: "memory");
  __builtin_amdgcn_s_barrier();               // LDS-only: skip store drain
  if (t == 0) {
    pA[bid] = red[0] + red[1] + red[2] + red[3];
    pB[bid] = red[4];
  }
#undef LOADX
#undef PACKX
#undef COMPUTE_MINRED
#undef EPILOGUE
}

__global__ void vq_fin(const float* __restrict__ pA,
                       const float* __restrict__ pB,
                       float* __restrict__ out) {
  const int t = threadIdx.x;                  // 512 threads, 512 partials
  float v = pA[t] + pB[t];
  v = wave_sum(v);
  __shared__ float r[8];
  if ((t & 63) == 0) r[t >> 6] = v;
  __syncthreads();
  if (t == 0) {
    float s = 0.f;
    #pragma unroll
    for (int i = 0; i < 8; ++i) s += r[i];
    out[0] = 1.25f * s * (1.0f / NELEM);
  }
}

extern "C" void kernel_launch(void* const* d_in, const int* in_sizes, int n_in,
                              void* d_out, int out_size, void* d_ws, size_t ws_size,
                              hipStream_t stream) {
  const float* X  = (const float*)d_in[0];   // [32,64,64,64] fp32
  const float* CB = (const float*)d_in[1];   // [512,64] fp32
  float* out = (float*)d_out;                // [0]=loss, [1..]=quantized_st
  char* ws = (char*)d_ws;
  unsigned short* aFg = (unsigned short*)ws;
  float* cn = (float*)(ws + 65536);
  float* pA = (float*)(ws + 67584);
  float* pB = (float*)(ws + 75776);
  (void)in_sizes; (void)n_in; (void)out_size; (void)ws_size;

  vq_prep<<<8, 512, 0, stream>>>(CB, aFg, cn);
  vq_main<<<NBLK, 256, 0, stream>>>(X, CB, aFg, cn, out, pA, pB);
  vq_fin<<<1, 512, 0, stream>>>(pA, pB, out);
}

// Round 7
// 34.657 us; speedup vs baseline: 2.9740x; 1.0074x over previous
//
#include <hip/hip_runtime.h>

#define DIM 64
#define HW 4096          // 64*64
#define NELEM 8388608.0f // 32*64*4096
#define NBLK 1024        // 128-col tiles

typedef __attribute__((ext_vector_type(8))) short short8;   // 8 x bf16
typedef __attribute__((ext_vector_type(4))) float f32x4;
typedef __attribute__((ext_vector_type(2))) float f32x2;

__device__ __forceinline__ unsigned short f2bf(float f) {
  unsigned int u = __builtin_bit_cast(unsigned int, f);
  u += 0x7fffu + ((u >> 16) & 1u);            // round-to-nearest-even
  return (unsigned short)(u >> 16);
}

__device__ __forceinline__ float wave_sum(float v) {
  #pragma unroll
  for (int off = 32; off >= 1; off >>= 1) v += __shfl_xor(v, off);
  return v;
}

// ws layout (bytes):
//  [0,      65536)  A-frags: bf16(-2*codebook), MFMA-fragment order (L2-hot)
//  [65536,  67584)  cnorm fp32 [512]
//  [67584,  71680)  per-block partial sum(x^2)      (1024 floats)
//  [75776,  79872)  per-block partial sum(min d2')  (1024 floats)

// ---------------- prep: codebook -> fragment order (once per call) ---------
__global__ void vq_prep(const float* __restrict__ CB,
                        unsigned short* __restrict__ aFg,
                        float* __restrict__ cn) {
  const int t = threadIdx.x;
  const int s = blockIdx.x * 512 + t;     // 0..4095 fragment slots
  const int chunk = s >> 7, ks = (s >> 6) & 1, ls = s & 63;
  const int code = chunk * 16 + (ls & 15);
  const int d0 = ks * 32 + (ls >> 4) * 8;
  const float* cp = CB + code * DIM + d0;
  float4 u0 = *(const float4*)cp;
  float4 u1 = *(const float4*)(cp + 4);
  short8 p;
  p[0]=(short)f2bf(-2.f*u0.x); p[1]=(short)f2bf(-2.f*u0.y);
  p[2]=(short)f2bf(-2.f*u0.z); p[3]=(short)f2bf(-2.f*u0.w);
  p[4]=(short)f2bf(-2.f*u1.x); p[5]=(short)f2bf(-2.f*u1.y);
  p[6]=(short)f2bf(-2.f*u1.z); p[7]=(short)f2bf(-2.f*u1.w);
  *(short8*)&aFg[s * 8] = p;
  if (blockIdx.x == 0) {                  // exact fp32 ||c_k||^2
    const float* c2 = CB + t * DIM;
    float sn = 0.f;
    #pragma unroll
    for (int i = 0; i < 16; ++i) {
      float4 u = *(const float4*)(c2 + i * 4);
      sn += u.x*u.x + u.y*u.y + u.z*u.z + u.w*u.w;
    }
    cn[t] = sn;
  }
}

// ---- main: 1024 blocks x 4 waves; 128-col tile; codes split across waves --
// R7: store-path A/B vs the proven 34.25us R1 base (byte-identical except):
// (a) output stores are PLAIN (nt removed) so L2 write-back can assemble the
//     +4B-misaligned partial lines into full lines before eviction (nt
//     streaming prevented merging -> DRAM RMW per partial line);
// (b) epilogue reordered h-innermost so the two 256B halves of each row
//     (which SPLIT a 64B line at col 63/64) issue back-to-back as one 512B
//     contiguous run.
// nt KEPT on X loads (protects L2 residency of aFg/CB).
// NO atomics/fences (same-addr device atomics ~100us convoy, prev session).
__global__ __launch_bounds__(256, 4)
void vq_main(const float* __restrict__ X, const float* __restrict__ CB,
             const unsigned short* __restrict__ aFg,
             const float* __restrict__ cng,
             float* __restrict__ out,
             float* __restrict__ pA, float* __restrict__ pB) {
  __shared__ __align__(16) unsigned short XF[16 * 64 * 8]; // 16 KB frag-order
  __shared__ float mW[4][128];                // per-wave packed mins per col
  __shared__ float red[8];

  const int t   = threadIdx.x;
  const int bid = blockIdx.x;
  // XCD-chunked swizzle: XCD x owns logical blocks [x*128,(x+1)*128)
  const int L   = ((bid & 7) << 7) | (bid >> 3);
  const int n   = L >> 5;                     // image (32 tiles of 128 cols)
  const int hw0 = (L & 31) << 7;              // 128-col tile
  const int wv  = t >> 6, lane = t & 63;
  const int g   = lane >> 4, lcol = lane & 15;

  const float* Xg = X + n * (DIM * HW) + hw0;

  // ---- stage X tile fp32->bf16 straight into fragment order --------------
  // thread t: d-rows db8*8..db8*8+7, cols {h*64 + cp*2, +1} for h=0,1
  const int db8 = t >> 5;                     // 0..7
  const int cp  = t & 31;                     // 0..31
  const int kss = db8 >> 2, gs = db8 & 3;
  f32x2 v[2][8];
  #pragma unroll
  for (int h = 0; h < 2; ++h)
    #pragma unroll
    for (int j = 0; j < 8; ++j)
      v[h][j] = __builtin_nontemporal_load(
          (const f32x2*)(Xg + (db8 * 8 + j) * HW + h * 64 + cp * 2));
  float sx2 = 0.f;
  #pragma unroll
  for (int h = 0; h < 2; ++h)
    #pragma unroll
    for (int j = 0; j < 8; ++j)
      sx2 += v[h][j].x * v[h][j].x + v[h][j].y * v[h][j].y;
  #pragma unroll
  for (int h = 0; h < 2; ++h) {
    #pragma unroll
    for (int ci = 0; ci < 2; ++ci) {
      const int cl   = cp * 2 + ci;           // 0..63 within half
      const int cb   = h * 4 + (cl >> 4);     // 0..7 col-block
      const int slot = (cb * 2 + kss) * 64 + gs * 16 + (cl & 15);
      const int swz  = slot ^ ((slot >> 3) & 7);
      short8 w;
      #pragma unroll
      for (int j = 0; j < 8; ++j)
        w[j] = (short)f2bf(ci ? v[h][j].y : v[h][j].x);
      *(short8*)&XF[swz * 8] = w;
    }
  }
  __syncthreads();

  // ---- B-frags from LDS: 16x ds_read_b128, conflict-free, resident -------
  const int swzl = lane ^ ((lane >> 3) & 7);
  short8 bfrag[2][4][2];
  #pragma unroll
  for (int h = 0; h < 2; ++h)
    #pragma unroll
    for (int cb2 = 0; cb2 < 4; ++cb2)
      #pragma unroll
      for (int ks = 0; ks < 2; ++ks)
        bfrag[h][cb2][ks] =
            *(const short8*)&XF[(((h * 4 + cb2) * 2 + ks) * 64 + swzl) * 8];

  // ---- this wave scans 128 codes = 8 chunks of 16, over all 128 cols -----
  float m1[8];
  #pragma unroll
  for (int cb = 0; cb < 8; ++cb) m1[cb] = 3.0e38f;

  const int chunk0 = wv * 8;
  #pragma unroll 2
  for (int i = 0; i < 8; ++i) {
    const int chunk = chunk0 + i;
    const short8 a0 = *(const short8*)&aFg[((chunk*2 + 0) * 64 + lane) * 8];
    const short8 a1 = *(const short8*)&aFg[((chunk*2 + 1) * 64 + lane) * 8];
    const int codebase = chunk * 16 + g * 4;
    const f32x4 cn = *(const f32x4*)&cng[codebase];
    #pragma unroll
    for (int h = 0; h < 2; ++h) {
      #pragma unroll
      for (int cb2 = 0; cb2 < 4; ++cb2) {
        f32x4 acc = cn;
        acc = __builtin_amdgcn_mfma_f32_16x16x32_bf16(a0, bfrag[h][cb2][0], acc, 0, 0, 0);
        acc = __builtin_amdgcn_mfma_f32_16x16x32_bf16(a1, bfrag[h][cb2][1], acc, 0, 0, 0);
        #pragma unroll
        for (int r = 0; r < 4; ++r) {
          unsigned int vb = __builtin_bit_cast(unsigned int, acc[r]);
          vb = (vb & 0xFFFFFE00u) | ((unsigned)(codebase + r) & 0x1FFu);
          m1[h * 4 + cb2] = fminf(m1[h * 4 + cb2], __builtin_bit_cast(float, vb));
        }
      }
    }
  }

  // combine lane-groups (disjoint code subsets, same col)
  #pragma unroll
  for (int cb = 0; cb < 8; ++cb) {
    m1[cb] = fminf(m1[cb], __shfl_xor(m1[cb], 16));
    m1[cb] = fminf(m1[cb], __shfl_xor(m1[cb], 32));
    if (g == 0) mW[wv][cb * 16 + lcol] = m1[cb];
  }
  __syncthreads();

  // ---- final per-col argmin ----------------------------------------------
  float msum = 0.f;
  const float* cqp[2];
  #pragma unroll
  for (int h = 0; h < 2; ++h) {
    const int c = h * 64 + lane;
    const float p = fminf(fminf(mW[0][c], mW[1][c]),
                          fminf(mW[2][c], mW[3][c]));
    const unsigned int b = __builtin_bit_cast(unsigned int, p);
    const int k = (int)(b & 511u);
    msum += __builtin_bit_cast(float, b & 0xFFFFFE00u);
    cqp[h] = CB + k * DIM + wv * 16;          // L2-hot gather base
  }

  // ---- epilogue: per row, h=0 then h=1 back-to-back (512B contiguous) ----
  float* opb = out + 1 + n * (DIM * HW) + hw0 + lane;
  #pragma unroll
  for (int i = 0; i < 4; ++i) {
    float4 u0 = *(const float4*)(cqp[0] + i * 4);
    float4 u1 = *(const float4*)(cqp[1] + i * 4);
    float* op = opb + (wv * 16 + i * 4) * HW;
    op[0 * HW]      = u0.x;  op[0 * HW + 64] = u1.x;  // row r: cols 0-63,64-127
    op[1 * HW]      = u0.y;  op[1 * HW + 64] = u1.y;
    op[2 * HW]      = u0.z;  op[2 * HW + 64] = u1.z;
    op[3 * HW]      = u0.w;  op[3 * HW + 64] = u1.w;
  }

  // ---- loss partials (no atomics; vq_fin reduces) ----
  float w1 = wave_sum(sx2);
  if (lane == 0) red[wv] = w1;
  if (wv == 0) {
    float w2 = wave_sum(msum);                // each col counted once
    if (lane == 0) red[4] = w2;
  }
  __syncthreads();
  if (t == 0) {
    pA[bid] = red[0] + red[1] + red[2] + red[3];
    pB[bid] = red[4];
  }
}

__global__ void vq_fin(const float* __restrict__ pA,
                       const float* __restrict__ pB,
                       float* __restrict__ out) {
  const int t = threadIdx.x;                  // 512 threads, 1024 partials
  f32x2 a = *(const f32x2*)&pA[t * 2];
  f32x2 c = *(const f32x2*)&pB[t * 2];
  float v = a.x + a.y + c.x + c.y;
  v = wave_sum(v);
  __shared__ float r[8];
  if ((t & 63) == 0) r[t >> 6] = v;
  __syncthreads();
  if (t == 0) {
    float s = 0.f;
    #pragma unroll
    for (int i = 0; i < 8; ++i) s += r[i];
    out[0] = 1.25f * s * (1.0f / NELEM);
  }
}

extern "C" void kernel_launch(void* const* d_in, const int* in_sizes, int n_in,
                              void* d_out, int out_size, void* d_ws, size_t ws_size,
                              hipStream_t stream) {
  const float* X  = (const float*)d_in[0];   // [32,64,64,64] fp32
  const float* CB = (const float*)d_in[1];   // [512,64] fp32
  float* out = (float*)d_out;                // [0]=loss, [1..]=quantized_st
  char* ws = (char*)d_ws;
  unsigned short* aFg = (unsigned short*)ws;
  float* cn = (float*)(ws + 65536);
  float* pA = (float*)(ws + 67584);
  float* pB = (float*)(ws + 75776);
  (void)in_sizes; (void)n_in; (void)out_size; (void)ws_size;

  vq_prep<<<8, 512, 0, stream>>>(CB, aFg, cn);
  vq_main<<<NBLK, 256, 0, stream>>>(X, CB, aFg, cn, out, pA, pB);
  vq_fin<<<1, 512, 0, stream>>>(pA, pB, out);
}